// Round 6
// baseline (3602.766 us; speedup 1.0000x reference)
//
#include <hip/hip_runtime.h>
#include <hip/hip_fp16.h>
#include <cstdint>

// mLstm  B=16, P=128, Q=256, D=128, H=128. fp32 in/out (verified R4/R5).
// R6: halve per-step L2 stream with fp16-pair packing of all streamed
// matrices; stagger tu/we to kill pass-B bank conflicts; fuse Whh-half of
// gates GEMV into pass A; gate-sum folded into the LSTM-cell pass.

__device__ __forceinline__ float bf2f(uint16_t u) {
  uint32_t x = ((uint32_t)u) << 16; float f; __builtin_memcpy(&f, &x, 4); return f;
}
__device__ __forceinline__ float load_in(const void* p, size_t i, int f32) {
  return f32 ? ((const float*)p)[i] : bf2f(((const uint16_t*)p)[i]);
}
__device__ __forceinline__ float frcp(float x) { return __builtin_amdgcn_rcpf(x); }
__device__ __forceinline__ float2 up2(uint32_t u) {   // fp16 pair -> 2 floats
  __half2 h; __builtin_memcpy(&h, &u, 4); return __half22float2(h);
}
__device__ __forceinline__ uint32_t pk2(float a, float b) {
  __half2 h = __floats2half2_rn(a, b);
  uint32_t u; __builtin_memcpy(&u, &h, 4); return u;
}

// ------------------------------------------------------------- detect kernel
__global__ void detect_kernel(const uint16_t* __restrict__ q16,
                              uint32_t* __restrict__ flag) {
  __shared__ int cnt;
  if (threadIdx.x == 0) cnt = 0;
  __syncthreads();
  int bad = 0;
  for (int i = threadIdx.x; i < 4096; i += 256) {
    int e = (q16[i] >> 7) & 0xFF;
    if (e > 0x8A) bad++;
  }
  atomicAdd(&cnt, bad);
  __syncthreads();
  if (threadIdx.x == 0) *flag = (cnt > 16) ? 1u : 0u;
}

// ------------------------------------------------- convert + pack (fp16 pairs)
// pf[262144]=p (fp32, tiny per-step reads)
// WrP2[64][128]  u32 = (Wr[j][2k2], Wr[j][2k2+1])          k-pairs
// wrb[128], wew[128], web[1]  fp32
// WgP2[64][256]  u32 = (Wg[i][2k2], Wg[i][2k2+1])  (k<128 half only)
// WT4 [96][512][2] u32: WT4[k4*1024+i*2+c] = (WT[4k4+2c][i], WT[4k4+2c+1][i])
//     WT[k][i] = k<256 ? Wih[i][k] : Whh[i][k-256]
// bb[512] = bih+bhh  fp32
__global__ void pack2(const void* __restrict__ p,
                      const void* __restrict__ Wr,  const void* __restrict__ Wrb_,
                      const void* __restrict__ Wew_, const void* __restrict__ Web_,
                      const void* __restrict__ Wg,
                      const void* __restrict__ Wih, const void* __restrict__ Whh,
                      const void* __restrict__ bih, const void* __restrict__ bhh,
                      float* __restrict__ pf,
                      uint32_t* __restrict__ WrP2, float* __restrict__ wrb,
                      float* __restrict__ wew, float* __restrict__ web,
                      uint32_t* __restrict__ WgP2,
                      uint32_t* __restrict__ WT4, float* __restrict__ bb,
                      const uint32_t* __restrict__ flag) {
  const int f32 = (int)*flag;
  long idx = (long)blockIdx.x * blockDim.x + threadIdx.x;
  if (idx < 262144) { pf[idx] = load_in(p, idx, f32); return; }
  idx -= 262144;
  if (idx < 8192) { int k2 = idx >> 7, j = idx & 127;
    WrP2[idx] = pk2(load_in(Wr, (size_t)j * 128 + 2 * k2, f32),
                    load_in(Wr, (size_t)j * 128 + 2 * k2 + 1, f32)); return; }
  idx -= 8192;
  if (idx < 128) { wrb[idx] = load_in(Wrb_, idx, f32); return; }
  idx -= 128;
  if (idx < 128) { wew[idx] = load_in(Wew_, idx, f32); return; }
  idx -= 128;
  if (idx < 1) { web[0] = load_in(Web_, 0, f32); return; }
  idx -= 1;
  if (idx < 16384) { int k2 = idx >> 8, i = idx & 255;
    WgP2[idx] = pk2(load_in(Wg, (size_t)i * 256 + 2 * k2, f32),
                    load_in(Wg, (size_t)i * 256 + 2 * k2 + 1, f32)); return; }
  idx -= 16384;
  if (idx < 98304) {
    int k4 = idx >> 10, rem = idx & 1023, i = rem >> 1, c = rem & 1;
    int k = k4 * 4 + 2 * c;
    float a, b2;
    if (k < 256) { a = load_in(Wih, (size_t)i * 256 + k, f32);
                   b2 = load_in(Wih, (size_t)i * 256 + k + 1, f32); }
    else         { a = load_in(Whh, (size_t)i * 128 + (k - 256), f32);
                   b2 = load_in(Whh, (size_t)i * 128 + (k - 255), f32); }
    WT4[idx] = pk2(a, b2); return; }
  idx -= 98304;
  if (idx < 512) { bb[idx] = load_in(bih, idx, f32) + load_in(bhh, idx, f32); }
}

// ------------------------------------------------------------ small GEMM
__global__ __launch_bounds__(256) void gemm_rw(const void* __restrict__ A, int lda,
                                               const void* __restrict__ W, int ldw,
                                               int w_off,
                                               const void* __restrict__ bias,
                                               float* __restrict__ out, int C,
                                               const uint32_t* __restrict__ flag) {
  __shared__ float A_l[16][128];
  __shared__ float W_l[64][129];
  const int f32 = (int)*flag;
  const int t = threadIdx.x;
  const int r0 = blockIdx.x * 16;
  for (int idx = t; idx < 16 * 128; idx += 256) {
    int rr = idx >> 7, kk = idx & 127;
    A_l[rr][kk] = load_in(A, (size_t)(r0 + rr) * lda + kk, f32);
  }
  const int c_l = t & 63, rg = t >> 6;
  for (int c0 = 0; c0 < C; c0 += 64) {
    __syncthreads();
    for (int idx = t; idx < 64 * 128; idx += 256) {
      int cc = idx >> 7, kk = idx & 127;
      W_l[cc][kk] = load_in(W, (size_t)w_off + (size_t)(c0 + cc) * ldw + kk, f32);
    }
    __syncthreads();
    float acc[4] = {0.f, 0.f, 0.f, 0.f};
    for (int k = 0; k < 128; k++) {
      float w = W_l[c_l][k];
#pragma unroll
      for (int x = 0; x < 4; x++) acc[x] = fmaf(A_l[rg * 4 + x][k], w, acc[x]);
    }
    float bv = load_in(bias, c0 + c_l, f32);
#pragma unroll
    for (int x = 0; x < 4; x++)
      out[(size_t)(r0 + rg * 4 + x) * C + c0 + c_l] = acc[x] + bv;
  }
}

// From whs (fp32) build:
//   tA2 [b][q][64]  u32 = (tanh(whs[q][2h2]), tanh(whs[q][2h2+1]))  h-pairs
//   whsP[b][q2][128] u32 = (whs[2q2][h], whs[2q2+1][h])             q-pairs
__global__ void tanh_pack(const float* __restrict__ whs,
                          uint32_t* __restrict__ tA2,
                          uint32_t* __restrict__ whsP) {
  int i = blockIdx.x * blockDim.x + threadIdx.x;  // 0..262143
  {
    int b = i >> 14, qq = (i >> 6) & 255, h2 = i & 63;
    const float* base = whs + (((size_t)b * 256 + qq) << 7) + h2 * 2;
    tA2[i] = pk2(tanhf(base[0]), tanhf(base[1]));
  }
  {
    int b = i >> 14, q2 = (i >> 7) & 127, h = i & 127;
    const float* c0 = whs + (((size_t)b * 256 + q2 * 2) << 7) + h;
    whsP[((size_t)b << 14) + q2 * 128 + h] = pk2(c0[0], c0[128]);
  }
}

// ---------------------------------------------------------- sequential kernel
// 16 blocks x 1024 threads; 10 barriers/step; ~610 KB/step/block L2 stream.
__global__ __launch_bounds__(1024, 4) void mlstm_seq4(
    const float* __restrict__ pf,       // [16][128][128] fp32
    const uint32_t* __restrict__ tA2g,  // [16][256][64]  fp16-pairs (h)
    const uint32_t* __restrict__ whsPg, // [16][128][128] fp16-pairs (q)
    const float* __restrict__ wht_g,    // [16][128][128] fp32
    const float* __restrict__ Gp_g,     // [16][128][256] fp32
    const uint32_t* __restrict__ WrP2,  // [64][128]
    const uint32_t* __restrict__ WgP2,  // [64][256]
    const uint32_t* __restrict__ WT4,   // [96][512][2]
    const float* __restrict__ bb,       // [512]
    const float* __restrict__ wrb,      // [128]
    const float* __restrict__ wew,      // [128]
    const float* __restrict__ web,      // [1]
    float* __restrict__ out) {          // [16][128][128] fp32
  const int b = blockIdx.x, t = threadIdx.x;

  __shared__ __align__(16) float part_s[1024];
  __shared__ __align__(16) float partFh_s[1024];
  __shared__ __align__(16) float partF_s[1024];
  __shared__ __align__(16) float e_s[256];
  __shared__ __align__(16) float sc_s[256];
  __shared__ __align__(16) float xh_s[256];
  __shared__ __align__(16) float alpha_s[128];
  __shared__ __align__(16) float h_s[128];
  __shared__ __align__(16) float c_s[128];
  __shared__ __align__(16) float wrb_s[128];
  __shared__ __align__(16) float bb_s[512];
  __shared__ __align__(16) float tu4[440];   // staggered: addr = h + 104*(h>>5)
  __shared__ __align__(16) float we4[440];
  __shared__ float inv_s, web_s;

  if (t < 128) { wrb_s[t] = wrb[t]; h_s[t] = 0.f; c_s[t] = 0.f;
                 we4[t + 104 * (t >> 5)] = wew[t]; }
  if (t < 512) bb_s[t] = bb[t];
  if (t == 0) web_s = web[0];

  const uint32_t* tA2b  = tA2g  + ((size_t)b << 14);
  const uint32_t* whsPb = whsPg + ((size_t)b << 14);

  const int jA = t & 127, kgA = t >> 7;     // A: 8 kgroups x 16 k (8 pairs)
  const int qiB = t >> 2, hgB = t & 3;      // B: 256 q x 4 hgroups(32 h)
  const int hD = t & 127, qgD = t >> 7;     // D: 8 qgroups x 32 q (16 pairs)
  const int iE = t & 255, kgE = t >> 8;     // E: 4 kgroups x 32 k (16 pairs)
  const int iF = t & 511, kgF = t >> 9;     // F/Fh: 2 kgroups
  __syncthreads();

  for (int st = 0; st < 128; st++) {
    // ---- A: h @ Wr^T partials (fp16 k-pairs)
    {
      float acc = 0.f;
#pragma unroll
      for (int r2 = 0; r2 < 8; r2++) {
        float2 w = up2(WrP2[(kgA * 8 + r2) * 128 + jA]);
        float2 hv = *(const float2*)&h_s[(kgA * 8 + r2) * 2];
        acc = fmaf(w.x, hv.x, acc); acc = fmaf(w.y, hv.y, acc);
      }
      part_s[kgA * 128 + jA] = acc;
    }
    // ---- Fh (fused): Whh-half of gates GEMV (k4 = 64..95), h known now
    {
      float acc = 0.f;
      const uint32_t* Wb = WT4 + (size_t)(64 + kgF * 16) * 1024 + iF * 2;
#pragma unroll
      for (int r4 = 0; r4 < 16; r4++) {
        uint2 w2 = *(const uint2*)(Wb + (size_t)r4 * 1024);
        float2 wa = up2(w2.x), wc = up2(w2.y);
        float4 x4 = *(const float4*)&h_s[kgF * 64 + r4 * 4];
        acc = fmaf(wa.x, x4.x, acc); acc = fmaf(wa.y, x4.y, acc);
        acc = fmaf(wc.x, x4.z, acc); acc = fmaf(wc.y, x4.w, acc);
      }
      partFh_s[kgF * 512 + iF] = acc;
    }
    __syncthreads();
    if (t < 128) {
      float u = wrb_s[t] + wht_g[((size_t)b * 128 + st) * 128 + t];
#pragma unroll
      for (int g = 0; g < 8; g++) u += part_s[g * 128 + t];
      tu4[t + 104 * (t >> 5)] = tanhf(u);
    }
    __syncthreads();

    // ---- B: scores via tanh addition identity (fp16 tA pairs, staggered tu/we)
    {
      const uint2* tAp = (const uint2*)(tA2b + qiB * 64 + hgB * 16);
      const float* tub = tu4 + hgB * 136;
      const float* wee = we4 + hgB * 136;
      float acc = 0.f;
#pragma unroll
      for (int jj = 0; jj < 8; jj++) {
        uint2 a2 = tAp[jj];
        float2 A0 = up2(a2.x), A1 = up2(a2.y);
        float4 U4 = *(const float4*)(tub + jj * 4);
        float4 W4 = *(const float4*)(wee + jj * 4);
        acc = fmaf((A0.x + U4.x) * frcp(fmaf(A0.x, U4.x, 1.f)), W4.x, acc);
        acc = fmaf((A0.y + U4.y) * frcp(fmaf(A0.y, U4.y, 1.f)), W4.y, acc);
        acc = fmaf((A1.x + U4.z) * frcp(fmaf(A1.x, U4.z, 1.f)), W4.z, acc);
        acc = fmaf((A1.y + U4.w) * frcp(fmaf(A1.y, U4.w, 1.f)), W4.w, acc);
      }
      acc += __shfl_xor(acc, 1);
      acc += __shfl_xor(acc, 2);
      if (hgB == 0) sc_s[qiB] = acc + web_s;
    }
    __syncthreads();

    // ---- C: softmax (wave 0), max-subtracted, 1/sum folded into alpha
    if (t < 64) {
      float s0 = sc_s[t], s1 = sc_s[t + 64], s2 = sc_s[t + 128], s3 = sc_s[t + 192];
      float mx = fmaxf(fmaxf(s0, s1), fmaxf(s2, s3));
#pragma unroll
      for (int d = 1; d < 64; d <<= 1) mx = fmaxf(mx, __shfl_xor(mx, d));
      float e0 = expf(s0 - mx), e1 = expf(s1 - mx),
            e2 = expf(s2 - mx), e3 = expf(s3 - mx);
      float sum = e0 + e1 + e2 + e3;
#pragma unroll
      for (int d = 1; d < 64; d <<= 1) sum += __shfl_xor(sum, d);
      e_s[t] = e0; e_s[t + 64] = e1; e_s[t + 128] = e2; e_s[t + 192] = e3;
      if (t == 0) inv_s = 1.0f / sum;
    }
    __syncthreads();

    // ---- D: alpha partials = sum_q e[q] * whs[q][h] (fp16 q-pairs)
    {
      float acc = 0.f;
#pragma unroll
      for (int r2 = 0; r2 < 16; r2++) {
        float2 w = up2(whsPb[(qgD * 16 + r2) * 128 + hD]);
        float2 ev = *(const float2*)&e_s[(qgD * 16 + r2) * 2];
        acc = fmaf(w.x, ev.x, acc); acc = fmaf(w.y, ev.y, acc);
      }
      part_s[qgD * 128 + hD] = acc;
    }
    __syncthreads();
    if (t < 128) {
      float a = 0.f;
#pragma unroll
      for (int g = 0; g < 8; g++) a += part_s[g * 128 + t];
      alpha_s[t] = a * inv_s;
    }
    __syncthreads();

    // ---- E: gate partials = sum_{k<128} Wg[i][k]*alpha[k] (fp16 k-pairs)
    {
      float acc = 0.f;
#pragma unroll
      for (int r2 = 0; r2 < 16; r2++) {
        float2 w = up2(WgP2[(kgE * 16 + r2) * 256 + iE]);
        float2 av = *(const float2*)&alpha_s[(kgE * 16 + r2) * 2];
        acc = fmaf(w.x, av.x, acc); acc = fmaf(w.y, av.y, acc);
      }
      part_s[kgE * 256 + iE] = acc;
    }
    __syncthreads();
    if (t < 256) {
      float g = Gp_g[((size_t)b * 128 + st) * 256 + t];
#pragma unroll
      for (int gg = 0; gg < 4; gg++) g += part_s[gg * 256 + t];
      float sg = 1.0f / (1.0f + expf(-g));
      float xv = (t < 128) ? alpha_s[t]
                           : pf[((size_t)b * 128 + st) * 128 + (t - 128)];
      xh_s[t] = sg * xv;
    }
    __syncthreads();

    // ---- F: x-half of gates GEMV (k4 = 0..63, fp16 pairs)
    {
      float acc = 0.f;
      const uint32_t* Wb = WT4 + (size_t)(kgF * 32) * 1024 + iF * 2;
#pragma unroll
      for (int r4 = 0; r4 < 32; r4++) {
        uint2 w2 = *(const uint2*)(Wb + (size_t)r4 * 1024);
        float2 wa = up2(w2.x), wc = up2(w2.y);
        float4 x4 = *(const float4*)&xh_s[kgF * 128 + r4 * 4];
        acc = fmaf(wa.x, x4.x, acc); acc = fmaf(wa.y, x4.y, acc);
        acc = fmaf(wc.x, x4.z, acc); acc = fmaf(wc.y, x4.w, acc);
      }
      partF_s[kgF * 512 + iF] = acc;
    }
    __syncthreads();

    // ---- G: gate sums + LSTM cell (i,f,g,o)
    if (t < 128) {
      float g0 = partFh_s[t]       + partFh_s[512 + t] + partF_s[t]       + partF_s[512 + t] + bb_s[t];
      float g1 = partFh_s[128 + t] + partFh_s[640 + t] + partF_s[128 + t] + partF_s[640 + t] + bb_s[128 + t];
      float g2 = partFh_s[256 + t] + partFh_s[768 + t] + partF_s[256 + t] + partF_s[768 + t] + bb_s[256 + t];
      float g3 = partFh_s[384 + t] + partFh_s[896 + t] + partF_s[384 + t] + partF_s[896 + t] + bb_s[384 + t];
      float iv = 1.0f / (1.0f + expf(-g0));
      float fv = 1.0f / (1.0f + expf(-g1));
      float gv = tanhf(g2);
      float ov = 1.0f / (1.0f + expf(-g3));
      float cn = fmaf(fv, c_s[t], iv * gv);
      float hn = ov * tanhf(cn);
      c_s[t] = cn; h_s[t] = hn;
      out[((size_t)b * 128 + st) * 128 + t] = hn;
    }
    __syncthreads();
  }
}

// ----------------------------------------------------------------- launcher
extern "C" void kernel_launch(void* const* d_in, const int* in_sizes, int n_in,
                              void* d_out, int out_size, void* d_ws, size_t ws_size,
                              hipStream_t stream) {
  static const int SZ_DICT[18] = {262144, 524288, 16384, 128, 16384, 128,
                                  16384, 128, 128, 1, 65536, 256,
                                  131072, 65536, 512, 512, 2048, 4096};
  static const int ALPHA2DICT[18] = {9, 8, 11, 10, 13, 12, 7, 6, 3, 2, 5, 4,
                                     15, 14, 0, 16, 1, 17};
  const void* in[18];
  for (int i = 0; i < 18; i++) in[i] = (i < n_in) ? d_in[i] : nullptr;

  bool dict_ok = true;
  int lim = (n_in < 16) ? n_in : 16;
  for (int i = 0; i < lim; i++) if (in_sizes[i] != SZ_DICT[i]) dict_ok = false;
  if (!dict_ok) {
    bool alpha_ok = true;
    for (int s = 0; s < n_in && s < 18; s++)
      if (in_sizes[s] != SZ_DICT[ALPHA2DICT[s]]) alpha_ok = false;
    if (alpha_ok)
      for (int s = 0; s < n_in && s < 18; s++) in[ALPHA2DICT[s]] = d_in[s];
  }

  const void* p   = in[0];  const void* q   = in[1];
  const void* Wsw = in[2];  const void* Wsb = in[3];
  const void* Wtw = in[4];  const void* Wtb = in[5];
  const void* Wrw = in[6];  const void* Wrb = in[7];
  const void* Wew = in[8];  const void* Web = in[9];
  const void* Wgw = in[10]; const void* Wgb = in[11];
  const void* Wih = in[12]; const void* Whh = in[13];
  const void* bih = in[14]; const void* bhh = in[15];

  float* ws = (float*)d_ws;
  float*    whs   = ws;                          // 524288 f
  uint32_t* tA2   = (uint32_t*)(whs + 524288);   // 262144 u32
  uint32_t* whsP  = tA2 + 262144;                // 262144 u32
  float*    pf    = (float*)(whsP + 262144);     // 262144 f
  float*    wht   = pf + 262144;                 // 262144 f
  float*    Gp    = wht + 262144;                // 524288 f
  uint32_t* WrP2  = (uint32_t*)(Gp + 524288);    // 8192 u32
  uint32_t* WgP2  = WrP2 + 8192;                 // 16384 u32
  uint32_t* WT4   = WgP2 + 16384;                // 98304 u32
  float*    bb    = (float*)(WT4 + 98304);       // 512 f
  float*    wrb   = bb + 512;                    // 128
  float*    wew   = wrb + 128;                   // 128
  float*    web   = wew + 128;                   // 4 (1 used)
  uint32_t* flag  = (uint32_t*)(web + 4);        // ~9.45 MB total

  hipLaunchKernelGGL(detect_kernel, dim3(1), dim3(256), 0, stream,
                     (const uint16_t*)q, flag);
  hipLaunchKernelGGL(pack2, dim3(1508), dim3(256), 0, stream,
                     p, Wrw, Wrb, Wew, Web, Wgw, Wih, Whh, bih, bhh,
                     pf, WrP2, wrb, wew, web, WgP2, WT4, bb, flag);
  // whs = q@Ws^T + Ws_b : 4096 rows x 128
  hipLaunchKernelGGL(gemm_rw, dim3(256), dim3(256), 0, stream,
                     q, 128, Wsw, 128, 0, Wsb, whs, 128, flag);
  // wht = p@Wt^T + Wt_b : 2048 rows x 128
  hipLaunchKernelGGL(gemm_rw, dim3(128), dim3(256), 0, stream,
                     p, 128, Wtw, 128, 0, Wtb, wht, 128, flag);
  // Gp = p@Wg[:,128:]^T + Wg_b : 2048 rows x 256
  hipLaunchKernelGGL(gemm_rw, dim3(128), dim3(256), 0, stream,
                     p, 128, Wgw, 256, 128, Wgb, Gp, 256, flag);
  hipLaunchKernelGGL(tanh_pack, dim3(1024), dim3(256), 0, stream,
                     whs, tA2, whsP);
  hipLaunchKernelGGL(mlstm_seq4, dim3(16), dim3(1024), 0, stream,
                     pf, tA2, whsP, wht, Gp, WrP2, WgP2, WT4, bb, wrb, wew,
                     web, (float*)d_out);
}

// Round 7
// 1735.963 us; speedup vs baseline: 2.0754x; 2.0754x over previous
//
#include <hip/hip_runtime.h>
#include <hip/hip_fp16.h>
#include <cstdint>

// mLstm  B=16, P=128, Q=256, D=128, H=128. fp32 in/out (verified R4/R5).
// R7: exact R5 phase skeleton (12us/step verified) + fp16 compression loaded
// as uint4 (16B/lane dwordx4 — R6's regression used 4-8B/lane loads) + R6's
// verified tu/we LDS stagger (conflicts 2.1M -> 0).

__device__ __forceinline__ float bf2f(uint16_t u) {
  uint32_t x = ((uint32_t)u) << 16; float f; __builtin_memcpy(&f, &x, 4); return f;
}
__device__ __forceinline__ float load_in(const void* p, size_t i, int f32) {
  return f32 ? ((const float*)p)[i] : bf2f(((const uint16_t*)p)[i]);
}
__device__ __forceinline__ float frcp(float x) { return __builtin_amdgcn_rcpf(x); }
__device__ __forceinline__ float2 up2(uint32_t u) {   // fp16 pair -> 2 floats
  __half2 h; __builtin_memcpy(&h, &u, 4); return __half22float2(h);
}
__device__ __forceinline__ uint32_t pk2(float a, float b) {
  __half2 h = __floats2half2_rn(a, b);
  uint32_t u; __builtin_memcpy(&u, &h, 4); return u;
}

// ------------------------------------------------------------- detect kernel
__global__ void detect_kernel(const uint16_t* __restrict__ q16,
                              uint32_t* __restrict__ flag) {
  __shared__ int cnt;
  if (threadIdx.x == 0) cnt = 0;
  __syncthreads();
  int bad = 0;
  for (int i = threadIdx.x; i < 4096; i += 256) {
    int e = (q16[i] >> 7) & 0xFF;
    if (e > 0x8A) bad++;
  }
  atomicAdd(&cnt, bad);
  __syncthreads();
  if (threadIdx.x == 0) *flag = (cnt > 16) ? 1u : 0u;
}

// ------------------------------------------------- convert + pack (fp16 uint4)
// All fp16 arrays are pair-packed, grouped 4 pairs (=8 scalars) per uint4 so
// the seq kernel issues only dwordx4 loads.
//   WrP4[(k8*128+j)*4+c] = (Wr[j][k8*8+2c], Wr[j][k8*8+2c+1])      k8<16
//   WgP4[(k8*256+i)*4+c] = (Wg[i][k8*8+2c], Wg[i][k8*8+2c+1])      k8<16 (k<128)
//   WT8 [(k8*512+i)*4+c] : k=k8*8+2c; WT[k][i]=k<256?Wih[i][k]:Whh[i][k-256]
//   bb[512]=bih+bhh; pf=p fp32; wrb/wew/web fp32.
__global__ void pack2(const void* __restrict__ p,
                      const void* __restrict__ Wr,  const void* __restrict__ Wrb_,
                      const void* __restrict__ Wew_, const void* __restrict__ Web_,
                      const void* __restrict__ Wg,
                      const void* __restrict__ Wih, const void* __restrict__ Whh,
                      const void* __restrict__ bih, const void* __restrict__ bhh,
                      float* __restrict__ pf,
                      uint32_t* __restrict__ WrP4, float* __restrict__ wrb,
                      float* __restrict__ wew, float* __restrict__ web,
                      uint32_t* __restrict__ WgP4,
                      uint32_t* __restrict__ WT8, float* __restrict__ bb,
                      const uint32_t* __restrict__ flag) {
  const int f32 = (int)*flag;
  long idx = (long)blockIdx.x * blockDim.x + threadIdx.x;
  if (idx < 262144) { pf[idx] = load_in(p, idx, f32); return; }
  idx -= 262144;
  if (idx < 8192) {
    int c = idx & 3, j = (idx >> 2) & 127, k8 = idx >> 9;
    int k = k8 * 8 + 2 * c;
    WrP4[idx] = pk2(load_in(Wr, (size_t)j * 128 + k, f32),
                    load_in(Wr, (size_t)j * 128 + k + 1, f32));
    return; }
  idx -= 8192;
  if (idx < 128) { wrb[idx] = load_in(Wrb_, idx, f32); return; }
  idx -= 128;
  if (idx < 128) { wew[idx] = load_in(Wew_, idx, f32); return; }
  idx -= 128;
  if (idx < 1) { web[0] = load_in(Web_, 0, f32); return; }
  idx -= 1;
  if (idx < 16384) {
    int c = idx & 3, i = (idx >> 2) & 255, k8 = idx >> 10;
    int k = k8 * 8 + 2 * c;
    WgP4[idx] = pk2(load_in(Wg, (size_t)i * 256 + k, f32),
                    load_in(Wg, (size_t)i * 256 + k + 1, f32));
    return; }
  idx -= 16384;
  if (idx < 98304) {
    int c = idx & 3, i = (idx >> 2) & 511, k8 = idx >> 11;
    int k = k8 * 8 + 2 * c;
    float a, b2;
    if (k < 256) { a = load_in(Wih, (size_t)i * 256 + k, f32);
                   b2 = load_in(Wih, (size_t)i * 256 + k + 1, f32); }
    else         { a = load_in(Whh, (size_t)i * 128 + (k - 256), f32);
                   b2 = load_in(Whh, (size_t)i * 128 + (k - 255), f32); }
    WT8[idx] = pk2(a, b2); return; }
  idx -= 98304;
  if (idx < 512) { bb[idx] = load_in(bih, idx, f32) + load_in(bhh, idx, f32); }
}

// ------------------------------------------------------------ small GEMM
__global__ __launch_bounds__(256) void gemm_rw(const void* __restrict__ A, int lda,
                                               const void* __restrict__ W, int ldw,
                                               int w_off,
                                               const void* __restrict__ bias,
                                               float* __restrict__ out, int C,
                                               const uint32_t* __restrict__ flag) {
  __shared__ float A_l[16][128];
  __shared__ float W_l[64][129];
  const int f32 = (int)*flag;
  const int t = threadIdx.x;
  const int r0 = blockIdx.x * 16;
  for (int idx = t; idx < 16 * 128; idx += 256) {
    int rr = idx >> 7, kk = idx & 127;
    A_l[rr][kk] = load_in(A, (size_t)(r0 + rr) * lda + kk, f32);
  }
  const int c_l = t & 63, rg = t >> 6;
  for (int c0 = 0; c0 < C; c0 += 64) {
    __syncthreads();
    for (int idx = t; idx < 64 * 128; idx += 256) {
      int cc = idx >> 7, kk = idx & 127;
      W_l[cc][kk] = load_in(W, (size_t)w_off + (size_t)(c0 + cc) * ldw + kk, f32);
    }
    __syncthreads();
    float acc[4] = {0.f, 0.f, 0.f, 0.f};
    for (int k = 0; k < 128; k++) {
      float w = W_l[c_l][k];
#pragma unroll
      for (int x = 0; x < 4; x++) acc[x] = fmaf(A_l[rg * 4 + x][k], w, acc[x]);
    }
    float bv = load_in(bias, c0 + c_l, f32);
#pragma unroll
    for (int x = 0; x < 4; x++)
      out[(size_t)(r0 + rg * 4 + x) * C + c0 + c_l] = acc[x] + bv;
  }
}

// From whs (fp32) build fp16 packs:
//   tA2 [b*16384 + q*64 + h2]             = (tanh pair over h)     (h2<64)
//   whsP4[b*16384 + q8*512 + h*4 + c]     = (whs[q8*8+2c][h], whs[q8*8+2c+1][h])
__global__ void tanh_pack(const float* __restrict__ whs,
                          uint32_t* __restrict__ tA2,
                          uint32_t* __restrict__ whsP4) {
  int i = blockIdx.x * blockDim.x + threadIdx.x;  // 0..262143
  {
    int b = i >> 14, qq = (i >> 6) & 255, h2 = i & 63;
    const float* base = whs + (((size_t)b * 256 + qq) << 7) + h2 * 2;
    tA2[i] = pk2(tanhf(base[0]), tanhf(base[1]));
  }
  {
    int b = i >> 14, rem = i & 16383;
    int q8 = rem >> 9, h = (rem >> 2) & 127, c = rem & 3;
    int q = q8 * 8 + 2 * c;
    const float* c0 = whs + (((size_t)b * 256 + q) << 7) + h;
    whsP4[i] = pk2(c0[0], c0[128]);
  }
}

// ---------------------------------------------------------- sequential kernel
// R5 skeleton: 16 blocks x 1024 threads, same phases/barriers; all streamed
// matrices fp16, every global load dwordx4 (16B/lane).
__global__ __launch_bounds__(1024, 4) void mlstm_seq5(
    const float* __restrict__ pf,        // [16][128][128] fp32
    const uint32_t* __restrict__ tA2g,   // fp16 pairs (h), uint4 rows
    const uint32_t* __restrict__ whsP4g, // fp16 pairs (q), uint4 rows
    const float* __restrict__ wht_g,     // [16][128][128] fp32
    const float* __restrict__ Gp_g,      // [16][128][256] fp32
    const uint32_t* __restrict__ WrP4,   // [16][128][4]
    const uint32_t* __restrict__ WgP4,   // [16][256][4]
    const uint32_t* __restrict__ WT8,    // [48][512][4]
    const float* __restrict__ bb,        // [512]
    const float* __restrict__ wrb,       // [128]
    const float* __restrict__ wew,       // [128]
    const float* __restrict__ web,       // [1]
    float* __restrict__ out) {           // [16][128][128] fp32
  const int b = blockIdx.x, t = threadIdx.x;

  __shared__ __align__(16) float part_s[1024];
  __shared__ __align__(16) float gates_s[512];
  __shared__ __align__(16) float xh_s[384];
  __shared__ __align__(16) float e_s[256];
  __shared__ __align__(16) float sc_s[256];
  __shared__ __align__(16) float alpha_s[128];
  __shared__ __align__(16) float h_s[128];
  __shared__ __align__(16) float c_s[128];
  __shared__ __align__(16) float wrb_s[128];
  __shared__ __align__(16) float tu4[440];   // staggered: addr = h + 104*(h>>5)
  __shared__ __align__(16) float we4[440];
  __shared__ float inv_s, web_s;

  if (t < 128) { wrb_s[t] = wrb[t]; h_s[t] = 0.f; c_s[t] = 0.f;
                 we4[t + 104 * (t >> 5)] = wew[t]; }
  if (t == 0) web_s = web[0];
  const float bb_r = (t < 512) ? bb[t] : 0.f;

  const uint32_t* tA2b   = tA2g   + ((size_t)b << 14);
  const uint32_t* whsP4b = whsP4g + ((size_t)b << 14);

  const int jA = t & 127, kgA = t >> 7;     // A: 8 kgroups x 16 k (2 uint4)
  const int qiB = t >> 2, hgB = t & 3;      // B: 256 q x 4 hgroups(32 h, 4 uint4)
  const int hD = t & 127, qgD = t >> 7;     // D: 8 qgroups x 32 q (4 uint4)
  const int iE = t & 255, kgE = t >> 8;     // E: 4 kgroups x 32 k (4 uint4)
  const int iF = t & 511, kgF = t >> 9;     // F: 2 kgroups x 192 k (24 uint4)
  __syncthreads();

  for (int st = 0; st < 128; st++) {
    // ---- A: h @ Wr^T partials (fp16 uint4: 8 k per load)
    {
      float acc = 0.f;
#pragma unroll
      for (int r = 0; r < 2; r++) {
        uint4 w4 = *(const uint4*)(WrP4 + (size_t)((kgA * 2 + r) * 128 + jA) * 4);
        float2 w0 = up2(w4.x), w1 = up2(w4.y), w2 = up2(w4.z), w3 = up2(w4.w);
        float4 h0 = *(const float4*)&h_s[(kgA * 2 + r) * 8];
        float4 h1 = *(const float4*)&h_s[(kgA * 2 + r) * 8 + 4];
        acc = fmaf(w0.x, h0.x, acc); acc = fmaf(w0.y, h0.y, acc);
        acc = fmaf(w1.x, h0.z, acc); acc = fmaf(w1.y, h0.w, acc);
        acc = fmaf(w2.x, h1.x, acc); acc = fmaf(w2.y, h1.y, acc);
        acc = fmaf(w3.x, h1.z, acc); acc = fmaf(w3.y, h1.w, acc);
      }
      part_s[kgA * 128 + jA] = acc;
    }
    __syncthreads();
    if (t < 128) {
      float u = wrb_s[t] + wht_g[((size_t)b * 128 + st) * 128 + t];
#pragma unroll
      for (int g = 0; g < 8; g++) u += part_s[g * 128 + t];
      tu4[t + 104 * (t >> 5)] = tanhf(u);
    }
    __syncthreads();

    // ---- B: scores via tanh addition identity (fp16 uint4, staggered tu/we)
    {
      const uint4* tAp = (const uint4*)(tA2b + qiB * 64 + hgB * 16);
      const float* tub = tu4 + hgB * 136;
      const float* wee = we4 + hgB * 136;
      float acc = 0.f;
#pragma unroll
      for (int jj = 0; jj < 4; jj++) {
        uint4 a4 = tAp[jj];
        float2 A0 = up2(a4.x), A1 = up2(a4.y), A2 = up2(a4.z), A3 = up2(a4.w);
        float4 U0 = *(const float4*)(tub + jj * 8);
        float4 U1 = *(const float4*)(tub + jj * 8 + 4);
        float4 W0 = *(const float4*)(wee + jj * 8);
        float4 W1 = *(const float4*)(wee + jj * 8 + 4);
        acc = fmaf((A0.x + U0.x) * frcp(fmaf(A0.x, U0.x, 1.f)), W0.x, acc);
        acc = fmaf((A0.y + U0.y) * frcp(fmaf(A0.y, U0.y, 1.f)), W0.y, acc);
        acc = fmaf((A1.x + U0.z) * frcp(fmaf(A1.x, U0.z, 1.f)), W0.z, acc);
        acc = fmaf((A1.y + U0.w) * frcp(fmaf(A1.y, U0.w, 1.f)), W0.w, acc);
        acc = fmaf((A2.x + U1.x) * frcp(fmaf(A2.x, U1.x, 1.f)), W1.x, acc);
        acc = fmaf((A2.y + U1.y) * frcp(fmaf(A2.y, U1.y, 1.f)), W1.y, acc);
        acc = fmaf((A3.x + U1.z) * frcp(fmaf(A3.x, U1.z, 1.f)), W1.z, acc);
        acc = fmaf((A3.y + U1.w) * frcp(fmaf(A3.y, U1.w, 1.f)), W1.w, acc);
      }
      acc += __shfl_xor(acc, 1);
      acc += __shfl_xor(acc, 2);
      if (hgB == 0) sc_s[qiB] = acc + web_s;
    }
    __syncthreads();

    // ---- C: softmax (wave 0), max-subtracted, 1/sum folded into alpha
    if (t < 64) {
      float s0 = sc_s[t], s1 = sc_s[t + 64], s2 = sc_s[t + 128], s3 = sc_s[t + 192];
      float mx = fmaxf(fmaxf(s0, s1), fmaxf(s2, s3));
#pragma unroll
      for (int d = 1; d < 64; d <<= 1) mx = fmaxf(mx, __shfl_xor(mx, d));
      float e0 = expf(s0 - mx), e1 = expf(s1 - mx),
            e2 = expf(s2 - mx), e3 = expf(s3 - mx);
      float sum = e0 + e1 + e2 + e3;
#pragma unroll
      for (int d = 1; d < 64; d <<= 1) sum += __shfl_xor(sum, d);
      e_s[t] = e0; e_s[t + 64] = e1; e_s[t + 128] = e2; e_s[t + 192] = e3;
      if (t == 0) inv_s = 1.0f / sum;
    }
    __syncthreads();

    // ---- D: alpha partials = sum_q e[q] * whs[q][h] (fp16 uint4: 8 q per load)
    {
      float acc = 0.f;
#pragma unroll
      for (int r = 0; r < 4; r++) {
        int q8 = qgD * 4 + r;
        uint4 w4 = *(const uint4*)(whsP4b + (size_t)(q8 * 512 + hD * 4));
        float2 w0 = up2(w4.x), w1 = up2(w4.y), w2 = up2(w4.z), w3 = up2(w4.w);
        float4 e0 = *(const float4*)&e_s[q8 * 8];
        float4 e1 = *(const float4*)&e_s[q8 * 8 + 4];
        acc = fmaf(w0.x, e0.x, acc); acc = fmaf(w0.y, e0.y, acc);
        acc = fmaf(w1.x, e0.z, acc); acc = fmaf(w1.y, e0.w, acc);
        acc = fmaf(w2.x, e1.x, acc); acc = fmaf(w2.y, e1.y, acc);
        acc = fmaf(w3.x, e1.z, acc); acc = fmaf(w3.y, e1.w, acc);
      }
      part_s[qgD * 128 + hD] = acc;
    }
    __syncthreads();
    if (t < 128) {
      float a = 0.f;
#pragma unroll
      for (int g = 0; g < 8; g++) a += part_s[g * 128 + t];
      alpha_s[t] = a * inv_s;
    }
    __syncthreads();

    // ---- E: gate partials = sum_{k<128} Wg[i][k]*alpha[k] (fp16 uint4)
    {
      float acc = 0.f;
#pragma unroll
      for (int r = 0; r < 4; r++) {
        int k8 = kgE * 4 + r;
        uint4 w4 = *(const uint4*)(WgP4 + (size_t)(k8 * 256 + iE) * 4);
        float2 w0 = up2(w4.x), w1 = up2(w4.y), w2 = up2(w4.z), w3 = up2(w4.w);
        float4 a0 = *(const float4*)&alpha_s[k8 * 8];
        float4 a1 = *(const float4*)&alpha_s[k8 * 8 + 4];
        acc = fmaf(w0.x, a0.x, acc); acc = fmaf(w0.y, a0.y, acc);
        acc = fmaf(w1.x, a0.z, acc); acc = fmaf(w1.y, a0.w, acc);
        acc = fmaf(w2.x, a1.x, acc); acc = fmaf(w2.y, a1.y, acc);
        acc = fmaf(w3.x, a1.z, acc); acc = fmaf(w3.y, a1.w, acc);
      }
      part_s[kgE * 256 + iE] = acc;
    }
    __syncthreads();
    if (t < 256) {
      float g = Gp_g[((size_t)b * 128 + st) * 256 + t];
#pragma unroll
      for (int gg = 0; gg < 4; gg++) g += part_s[gg * 256 + t];
      float sg = 1.0f / (1.0f + expf(-g));
      float xv = (t < 128) ? alpha_s[t]
                           : pf[((size_t)b * 128 + st) * 128 + (t - 128)];
      xh_s[t] = sg * xv;
    } else if (t < 384) {
      xh_s[t] = h_s[t - 256];
    }
    __syncthreads();

    // ---- F: gates partials = sum_k WT[k][i]*xh[k] (fp16 uint4: 8 k per load)
    {
      float acc = 0.f;
#pragma unroll 8
      for (int r = 0; r < 24; r++) {
        int k8 = kgF * 24 + r;
        uint4 w4 = *(const uint4*)(WT8 + ((size_t)k8 * 512 + iF) * 4);
        float2 w0 = up2(w4.x), w1 = up2(w4.y), w2 = up2(w4.z), w3 = up2(w4.w);
        float4 x0 = *(const float4*)&xh_s[k8 * 8];
        float4 x1 = *(const float4*)&xh_s[k8 * 8 + 4];
        acc = fmaf(w0.x, x0.x, acc); acc = fmaf(w0.y, x0.y, acc);
        acc = fmaf(w1.x, x0.z, acc); acc = fmaf(w1.y, x0.w, acc);
        acc = fmaf(w2.x, x1.x, acc); acc = fmaf(w2.y, x1.y, acc);
        acc = fmaf(w3.x, x1.z, acc); acc = fmaf(w3.y, x1.w, acc);
      }
      part_s[kgF * 512 + iF] = acc;
    }
    __syncthreads();
    if (t < 512) gates_s[t] = part_s[t] + part_s[512 + t] + bb_r;
    __syncthreads();

    // ---- G: LSTM cell (i,f,g,o)
    if (t < 128) {
      float iv = 1.0f / (1.0f + expf(-gates_s[t]));
      float fv = 1.0f / (1.0f + expf(-gates_s[128 + t]));
      float gv = tanhf(gates_s[256 + t]);
      float ov = 1.0f / (1.0f + expf(-gates_s[384 + t]));
      float cn = fmaf(fv, c_s[t], iv * gv);
      float hn = ov * tanhf(cn);
      c_s[t] = cn; h_s[t] = hn;
      out[((size_t)b * 128 + st) * 128 + t] = hn;
    }
    __syncthreads();
  }
}

// ----------------------------------------------------------------- launcher
extern "C" void kernel_launch(void* const* d_in, const int* in_sizes, int n_in,
                              void* d_out, int out_size, void* d_ws, size_t ws_size,
                              hipStream_t stream) {
  static const int SZ_DICT[18] = {262144, 524288, 16384, 128, 16384, 128,
                                  16384, 128, 128, 1, 65536, 256,
                                  131072, 65536, 512, 512, 2048, 4096};
  static const int ALPHA2DICT[18] = {9, 8, 11, 10, 13, 12, 7, 6, 3, 2, 5, 4,
                                     15, 14, 0, 16, 1, 17};
  const void* in[18];
  for (int i = 0; i < 18; i++) in[i] = (i < n_in) ? d_in[i] : nullptr;

  bool dict_ok = true;
  int lim = (n_in < 16) ? n_in : 16;
  for (int i = 0; i < lim; i++) if (in_sizes[i] != SZ_DICT[i]) dict_ok = false;
  if (!dict_ok) {
    bool alpha_ok = true;
    for (int s = 0; s < n_in && s < 18; s++)
      if (in_sizes[s] != SZ_DICT[ALPHA2DICT[s]]) alpha_ok = false;
    if (alpha_ok)
      for (int s = 0; s < n_in && s < 18; s++) in[ALPHA2DICT[s]] = d_in[s];
  }

  const void* p   = in[0];  const void* q   = in[1];
  const void* Wsw = in[2];  const void* Wsb = in[3];
  const void* Wtw = in[4];  const void* Wtb = in[5];
  const void* Wrw = in[6];  const void* Wrb = in[7];
  const void* Wew = in[8];  const void* Web = in[9];
  const void* Wgw = in[10]; const void* Wgb = in[11];
  const void* Wih = in[12]; const void* Whh = in[13];
  const void* bih = in[14]; const void* bhh = in[15];

  float* ws = (float*)d_ws;
  float*    whs   = ws;                          // 524288 f
  uint32_t* tA2   = (uint32_t*)(whs + 524288);   // 262144 u32
  uint32_t* whsP4 = tA2 + 262144;                // 262144 u32
  float*    pf    = (float*)(whsP4 + 262144);    // 262144 f
  float*    wht   = pf + 262144;                 // 262144 f
  float*    Gp    = wht + 262144;                // 524288 f
  uint32_t* WrP4  = (uint32_t*)(Gp + 524288);    // 8192 u32
  uint32_t* WgP4  = WrP4 + 8192;                 // 16384 u32
  uint32_t* WT8   = WgP4 + 16384;                // 98304 u32
  float*    bb    = (float*)(WT8 + 98304);       // 512 f
  float*    wrb   = bb + 512;                    // 128
  float*    wew   = wrb + 128;                   // 128
  float*    web   = wew + 128;                   // 4 (1 used)
  uint32_t* flag  = (uint32_t*)(web + 4);        // ~9.45 MB total

  hipLaunchKernelGGL(detect_kernel, dim3(1), dim3(256), 0, stream,
                     (const uint16_t*)q, flag);
  hipLaunchKernelGGL(pack2, dim3(1508), dim3(256), 0, stream,
                     p, Wrw, Wrb, Wew, Web, Wgw, Wih, Whh, bih, bhh,
                     pf, WrP4, wrb, wew, web, WgP4, WT8, bb, flag);
  // whs = q@Ws^T + Ws_b : 4096 rows x 128
  hipLaunchKernelGGL(gemm_rw, dim3(256), dim3(256), 0, stream,
                     q, 128, Wsw, 128, 0, Wsb, whs, 128, flag);
  // wht = p@Wt^T + Wt_b : 2048 rows x 128
  hipLaunchKernelGGL(gemm_rw, dim3(128), dim3(256), 0, stream,
                     p, 128, Wtw, 128, 0, Wtb, wht, 128, flag);
  // Gp = p@Wg[:,128:]^T + Wg_b : 2048 rows x 256
  hipLaunchKernelGGL(gemm_rw, dim3(128), dim3(256), 0, stream,
                     p, 128, Wgw, 256, 128, Wgb, Gp, 256, flag);
  hipLaunchKernelGGL(tanh_pack, dim3(1024), dim3(256), 0, stream,
                     whs, tA2, whsP4);
  hipLaunchKernelGGL(mlstm_seq5, dim3(16), dim3(1024), 0, stream,
                     pf, tA2, whsP4, wht, Gp, WrP4, WgP4, WT8, bb, wrb, wew,
                     web, (float*)d_out);
}